// Round 2
// baseline (99.150 us; speedup 1.0000x reference)
//
#include <hip/hip_runtime.h>
#include <hip/hip_bf16.h>

#define EPS 1e-6f

typedef __attribute__((ext_vector_type(8))) __bf16 bf16x8;
typedef __attribute__((ext_vector_type(4))) float f32x4;

__device__ inline unsigned short f2bf_rtne(float f, float* back) {
    unsigned int u = __float_as_uint(f);
    unsigned int r = (u + 0x7FFFu + ((u >> 16) & 1u)) >> 16;
    if (back) *back = __uint_as_float(r << 16);
    return (unsigned short)r;
}

// split into (hi, lo) bf16 + row sum of squares (prototypes).
__global__ void split_rows(const float* __restrict__ in,
                           unsigned short* __restrict__ hi,
                           unsigned short* __restrict__ lo,
                           float* __restrict__ sq, int R, int D) {
    int wid = (blockIdx.x * blockDim.x + threadIdx.x) >> 6;
    int lane = threadIdx.x & 63;
    if (wid >= R) return;
    const float4* rp = (const float4*)(in + (size_t)wid * D);
    ushort4* hp = (ushort4*)(hi + (size_t)wid * D);
    ushort4* lp = (ushort4*)(lo + (size_t)wid * D);
    float s = 0.f;
    int nvec = D >> 2;
    for (int j = lane; j < nvec; j += 64) {
        float4 v = rp[j];
        float fv[4] = {v.x, v.y, v.z, v.w};
        ushort4 h4, l4;
        unsigned short* hh = (unsigned short*)&h4;
        unsigned short* ll = (unsigned short*)&l4;
#pragma unroll
        for (int i = 0; i < 4; ++i) {
            float f = fv[i];
            s += f * f;
            float hb;
            hh[i] = f2bf_rtne(f, &hb);
            ll[i] = f2bf_rtne(f - hb, nullptr);
        }
        hp[j] = h4;
        lp[j] = l4;
    }
#pragma unroll
    for (int off = 32; off; off >>= 1) s += __shfl_down(s, off);
    if (lane == 0) sq[wid] = s;
}

// split x: hi only + row sum of squares (x_lo term dropped from the GEMM).
__global__ void split_rows_hi(const float* __restrict__ in,
                              unsigned short* __restrict__ hi,
                              float* __restrict__ sq, int R, int D) {
    int wid = (blockIdx.x * blockDim.x + threadIdx.x) >> 6;
    int lane = threadIdx.x & 63;
    if (wid >= R) return;
    const float4* rp = (const float4*)(in + (size_t)wid * D);
    ushort4* hp = (ushort4*)(hi + (size_t)wid * D);
    float s = 0.f;
    int nvec = D >> 2;
    for (int j = lane; j < nvec; j += 64) {
        float4 v = rp[j];
        float fv[4] = {v.x, v.y, v.z, v.w};
        ushort4 h4;
        unsigned short* hh = (unsigned short*)&h4;
#pragma unroll
        for (int i = 0; i < 4; ++i) {
            float f = fv[i];
            s += f * f;
            hh[i] = f2bf_rtne(f, nullptr);
        }
        hp[j] = h4;
    }
#pragma unroll
    for (int off = 32; off; off >>= 1) s += __shfl_down(s, off);
    if (lane == 0) sq[wid] = s;
}

// ---------------------------------------------------------------------------
// pass 2: 256x256 8-phase MFMA GEMM, 16x16x32 (conflict-free swizzle),
// K_eff = 2*K segments: dots = xhi.phi + xhi.plo.
// m201 double-barrier phase template:
//   { ds_reads; stage 1 half-tile; [lgkmcnt(8) if 12 reads];
//     s_barrier; lgkmcnt(0)+sched_barrier; setprio(1); 16 MFMA; setprio(0);
//     s_barrier }
// Counted vmcnt(4) once per K-tile (ph4/ph8), placed before the pre-MFMA
// barrier (per-wave wait, so post-barrier ALL waves' loads except the newest
// 4 have landed). Epilogue staged through LDS for full-line f32x4 stores.
// out = dots^2 / (xsq + psq - 2*dots + eps)
// ---------------------------------------------------------------------------
__global__ __launch_bounds__(512, 2) void yat_mfma8(
    const unsigned short* __restrict__ Ahi,
    const unsigned short* __restrict__ Phi, const unsigned short* __restrict__ Plo,
    const float* __restrict__ xsq, const float* __restrict__ psq,
    float* __restrict__ out, int M, int N, int K) {

    __shared__ __align__(128) char sm[131072];   // 2 slots x (A 32KB + B 32KB)
    const char* smc = (const char*)sm;

    const int t = threadIdx.x;
    const int lane = t & 63;
    const int wid = t >> 6;        // 0..7
    const int wm = wid >> 2;       // 0..1  (row half of block)
    const int wn = wid & 3;        // 0..3  (col quarter of block)

    // T1: bijective XCD swizzle (total % 8 == 0 guaranteed by launch guard)
    const int nbx = N >> 8;
    const int nby = M >> 8;
    const int total = nbx * nby;
    int bid = blockIdx.x;
    bid = (bid & 7) * (total >> 3) + (bid >> 3);
    const int by = bid / nbx;
    const int bx = bid - by * nbx;
    const int brow = by << 8;
    const int bcol = bx << 8;

    const int KT = K >> 6;          // K-tiles per segment (16)
    const int NKT = 2 * KT;         // 32 (segments: hi.hi, hi.lo)
    const int NIT = NKT >> 1;       // 16

    f32x4 acc[8][4];
#pragma unroll
    for (int i = 0; i < 8; ++i)
#pragma unroll
        for (int j = 0; j < 4; ++j) acc[i][j] = (f32x4){0.f, 0.f, 0.f, 0.f};

    const int arow = lane & 15;           // fragment row/col within 16
    const int kq16 = (lane >> 4) * 16;    // byte offset of k-slot within 32-k half

    // stage one half-tile (16KB, 2 x global_load_lds per wave) of tile kt.
    // ht: 0=A-rows[0,128) 1=A-rows[128,256) 2=B-rows[0,128) 3=B-rows[128,256)
    const int stg_colb = (((lane & 7) ^ (lane >> 3)) << 4);  // pre-swizzled src col
    const size_t rowBytes = (size_t)K * 2;
    auto stage_ht = [&](int kt, int ht) {
        const int slot = kt & 1;
        const unsigned short* base;
        int rowbase;
        if (ht < 2) { base = Ahi; rowbase = brow; }
        else        { base = (kt >= KT) ? Plo : Phi; rowbase = bcol; }
        int kk = (kt >= KT) ? kt - KT : kt;
        const size_t k0b = (size_t)kk << 7;      // 64 elems * 2B
        const int half = ht & 1;
        char* lbase = (char*)sm + slot * 65536 + ((ht < 2) ? 0 : 32768) + half * 16384;
#pragma unroll
        for (int l = 0; l < 2; ++l) {
            int rl = (l * 8 + wid) * 8 + (lane >> 3);
            int grow = rowbase + half * 128 + rl;
            const char* src = (const char*)base + (size_t)grow * rowBytes + k0b + stg_colb;
            __builtin_amdgcn_global_load_lds(
                (const __attribute__((address_space(1))) void*)src,
                (__attribute__((address_space(3))) void*)(lbase + (l * 8 + wid) * 1024),
                16, 0, 0);
        }
    };

    bf16x8 af[4][2];              // current A-half frags (overwritten ph3/ph7)
    bf16x8 bf0[2][2], bf1[2][2];  // B-quarter frags, live across the tile

#define READ_A(slot, mh) do {                                                  \
    _Pragma("unroll")                                                          \
    for (int mi_ = 0; mi_ < 4; ++mi_) {                                        \
        int r_ = wm * 128 + (mh) * 64 + mi_ * 16 + arow;                       \
        const char* p_ = smc + (slot) * 65536 + r_ * 128;                      \
        int s_ = (r_ & 7) << 4;                                                \
        af[mi_][0] = *(const bf16x8*)(p_ + (kq16 ^ s_));                       \
        af[mi_][1] = *(const bf16x8*)(p_ + ((64 + kq16) ^ s_));                \
    }                                                                          \
} while (0)

#define READ_B(slot, nh, dst) do {                                             \
    _Pragma("unroll")                                                          \
    for (int ni_ = 0; ni_ < 2; ++ni_) {                                        \
        int r_ = wn * 64 + (nh) * 32 + ni_ * 16 + arow;                        \
        const char* p_ = smc + (slot) * 65536 + 32768 + r_ * 128;              \
        int s_ = (r_ & 7) << 4;                                                \
        dst[ni_][0] = *(const bf16x8*)(p_ + (kq16 ^ s_));                      \
        dst[ni_][1] = *(const bf16x8*)(p_ + ((64 + kq16) ^ s_));               \
    }                                                                          \
} while (0)

#define MFMA_Q(mh, nh, bset) do {                                              \
    __builtin_amdgcn_s_setprio(1);                                             \
    _Pragma("unroll")                                                          \
    for (int kk_ = 0; kk_ < 2; ++kk_)                                          \
        _Pragma("unroll")                                                      \
        for (int mi_ = 0; mi_ < 4; ++mi_)                                      \
            _Pragma("unroll")                                                  \
            for (int ni_ = 0; ni_ < 2; ++ni_)                                  \
                acc[(mh) * 4 + mi_][(nh) * 2 + ni_] =                          \
                    __builtin_amdgcn_mfma_f32_16x16x32_bf16(                   \
                        af[mi_][kk_], bset[ni_][kk_],                          \
                        acc[(mh) * 4 + mi_][(nh) * 2 + ni_], 0, 0, 0);         \
    __builtin_amdgcn_s_setprio(0);                                             \
} while (0)

#define BARX() do {                                                            \
    __builtin_amdgcn_s_barrier();                                              \
    __builtin_amdgcn_sched_barrier(0);                                         \
    asm volatile("" ::: "memory");                                             \
} while (0)
#define LGKM0() do {                                                           \
    asm volatile("s_waitcnt lgkmcnt(0)" ::: "memory");                         \
    __builtin_amdgcn_sched_barrier(0);                                         \
} while (0)
#define LGKM8() asm volatile("s_waitcnt lgkmcnt(8)" ::: "memory")
#define VMCNT(n) asm volatile("s_waitcnt vmcnt(" #n ")" ::: "memory")

    // prologue: stage T0 fully + T1.B halves; T0 resident; barrier.
    stage_ht(0, 0); stage_ht(0, 1); stage_ht(0, 2); stage_ht(0, 3);
    stage_ht(1, 2); stage_ht(1, 3);
    VMCNT(4);
    BARX();

    for (int it = 0; it < NIT; ++it) {
        const int T1 = 2 * it + 1, T2 = 2 * it + 2, T3 = 2 * it + 3;
        const bool more = (T2 < NKT);

        // ---- tile T0 (slot0) ----
        // ph1: 12 ds_reads + stage || bar || MFMA Q00 || bar
        READ_A(0, 0); READ_B(0, 0, bf0);
        stage_ht(T1, 0);
        LGKM8();
        BARX();
        LGKM0();
        MFMA_Q(0, 0, bf0);
        BARX();
        // ph2: 4 ds_reads + stage || bar || MFMA Q01 || bar
        READ_B(0, 1, bf1);
        stage_ht(T1, 1);
        BARX();
        LGKM0();
        MFMA_Q(0, 1, bf1);
        BARX();
        // ph3: 8 ds_reads + stage || bar || MFMA Q10 || bar
        READ_A(0, 1);
        if (more) stage_ht(T2, 2);
        BARX();
        LGKM0();
        MFMA_Q(1, 0, bf0);
        BARX();
        // ph4: stage + counted vmcnt || bar || MFMA Q11 || bar
        if (more) stage_ht(T2, 3);
        if (more) { VMCNT(4); } else { VMCNT(0); }
        BARX();
        MFMA_Q(1, 1, bf1);
        BARX();

        // ---- tile T1 (slot1) ----
        // ph5
        READ_A(1, 0); READ_B(1, 0, bf0);
        if (more) stage_ht(T2, 0);
        LGKM8();
        BARX();
        LGKM0();
        MFMA_Q(0, 0, bf0);
        BARX();
        // ph6
        READ_B(1, 1, bf1);
        if (more) stage_ht(T2, 1);
        BARX();
        LGKM0();
        MFMA_Q(0, 1, bf1);
        BARX();
        // ph7
        READ_A(1, 1);
        if (more) stage_ht(T3, 2);
        BARX();
        LGKM0();
        MFMA_Q(1, 0, bf0);
        BARX();
        // ph8
        if (more) stage_ht(T3, 3);
        if (more) { VMCNT(4); }
        BARX();
        MFMA_Q(1, 1, bf1);
        BARX();
    }

#undef READ_A
#undef READ_B
#undef MFMA_Q
#undef BARX
#undef LGKM0
#undef LGKM8
#undef VMCNT

    // epilogue: score = d^2 / (xsq + psq - 2d + eps), staged through LDS so
    // global stores are full 1KB-per-wave dwordx4 rows (no partial-line
    // write amplification). Two passes of 128 rows (wm half each).
    // Swizzle convention: logical (row, col) stored at physical col ^ swz(row),
    // swz(row) = ((row>>2)&1)<<4. Writer swizzles; reader un-swizzles by
    // reading physical (lane*4)^swz — which holds LOGICAL cols [lane*4,+3] —
    // and stores to logical global column bcol + lane*4.
    float* smf = (float*)sm;
#pragma unroll
    for (int pass = 0; pass < 2; ++pass) {
        __syncthreads();
        if (wm == pass) {
#pragma unroll
            for (int ni = 0; ni < 4; ++ni) {
                int lc = wn * 64 + ni * 16 + arow;
                float ps = psq[bcol + lc];
#pragma unroll
                for (int mi = 0; mi < 8; ++mi) {
                    f32x4 c = acc[mi][ni];
                    int lr0 = mi * 16 + (lane >> 4) * 4;   // local row, mult of 4
                    int grow0 = brow + pass * 128 + lr0;
                    float4 xs4 = *(const float4*)(xsq + grow0);
                    float xsv[4] = {xs4.x, xs4.y, xs4.z, xs4.w};
                    int lcs = lc ^ (((lr0 >> 2) & 1) << 4);  // phys col (same for j<4)
#pragma unroll
                    for (int j = 0; j < 4; ++j) {
                        float dv = c[j];
                        float denom = xsv[j] + ps - 2.0f * dv + EPS;
                        smf[(lr0 + j) * 256 + lcs] = dv * dv / denom;
                    }
                }
            }
        }
        __syncthreads();
#pragma unroll
        for (int rr = 0; rr < 16; ++rr) {
            int r = wid * 16 + rr;
            int swz = ((r >> 2) & 1) << 4;
            int c0 = lane * 4;                              // logical col
            f32x4 v = *(const f32x4*)(smf + r * 256 + (c0 ^ swz));
            *(f32x4*)(out + (size_t)(brow + pass * 128 + r) * N + bcol + c0) = v;
        }
    }
}

__global__ void yat_fallback(const float* __restrict__ x, const float* __restrict__ p,
                             float* __restrict__ out, int B, int P, int D) {
    __shared__ float xs[1024];
    int b = blockIdx.x;
    int pc = blockIdx.y * 256 + threadIdx.x;
    for (int i = threadIdx.x; i < D; i += 256) xs[i] = x[(size_t)b * D + i];
    __syncthreads();
    if (pc >= P) return;
    float dot = 0.f, psq = 0.f, xsq = 0.f;
    for (int k = 0; k < D; ++k) {
        float pv = p[(size_t)pc * D + k];
        float xv = xs[k];
        dot += xv * pv;
        psq += pv * pv;
        xsq += xv * xv;
    }
    float denom = xsq + psq - 2.f * dot + EPS;
    out[(size_t)b * P + pc] = dot * dot / denom;
}

extern "C" void kernel_launch(void* const* d_in, const int* in_sizes, int n_in,
                              void* d_out, int out_size, void* d_ws, size_t ws_size,
                              hipStream_t stream) {
    const float* x = (const float*)d_in[0];
    const float* p = (const float*)d_in[1];
    float* out = (float*)d_out;

    const int D = 1024;
    const int B = in_sizes[0] / D;
    const int P = in_sizes[1] / D;

    size_t need = ((size_t)B * D + 2 * (size_t)P * D) * 2 + ((size_t)B + P) * 4;
    int nblocks = (B / 256) * (P / 256);
    if (ws_size < need || (B % 256) || (P % 256) || (D % 64) || (nblocks % 8)) {
        yat_fallback<<<dim3(B, (P + 255) / 256), 256, 0, stream>>>(x, p, out, B, P, D);
        return;
    }

    unsigned short* xhi = (unsigned short*)d_ws;
    unsigned short* phi = xhi + (size_t)B * D;
    unsigned short* plo = phi + (size_t)P * D;
    float* xsq = (float*)(plo + (size_t)P * D);
    float* psq = xsq + B;

    split_rows_hi<<<(B + 3) / 4, 256, 0, stream>>>(x, xhi, xsq, B, D);
    split_rows<<<(P + 3) / 4, 256, 0, stream>>>(p, phi, plo, psq, P, D);

    yat_mfma8<<<dim3(nblocks), 512, 0, stream>>>(xhi, phi, plo, xsq, psq,
                                                 out, B, P, D);
}

// Round 3
// 72.020 us; speedup vs baseline: 1.3767x; 1.3767x over previous
//
#include <hip/hip_runtime.h>
#include <hip/hip_bf16.h>

#define EPS 1e-6f

typedef __attribute__((ext_vector_type(8))) __bf16 bf16x8;
typedef __attribute__((ext_vector_type(4))) float f32x4;

__device__ inline unsigned short f2bf_rtne(float f) {
    unsigned int u = __float_as_uint(f);
    unsigned int r = (u + 0x7FFFu + ((u >> 16) & 1u)) >> 16;
    return (unsigned short)r;
}

// merged split: rows [0,B) = x -> xhi/xsq ; rows [B,B+P) = p -> phi/psq.
// bf16 hi (RTNE) + f32 row sum of squares. One wave per row.
__global__ void split_all(const float* __restrict__ x, const float* __restrict__ p,
                          unsigned short* __restrict__ xhi, unsigned short* __restrict__ phi,
                          float* __restrict__ xsq, float* __restrict__ psq,
                          int B, int P, int D) {
    int wid = (blockIdx.x * blockDim.x + threadIdx.x) >> 6;
    int lane = threadIdx.x & 63;
    if (wid >= B + P) return;
    const float* in;
    unsigned short* hi;
    float* sq;
    if (wid < B) {
        in = x + (size_t)wid * D;
        hi = xhi + (size_t)wid * D;
        sq = xsq + wid;
    } else {
        int r = wid - B;
        in = p + (size_t)r * D;
        hi = phi + (size_t)r * D;
        sq = psq + r;
    }
    const float4* rp = (const float4*)in;
    ushort4* hp = (ushort4*)hi;
    float s = 0.f;
    int nvec = D >> 2;
    for (int j = lane; j < nvec; j += 64) {
        float4 v = rp[j];
        float fv[4] = {v.x, v.y, v.z, v.w};
        ushort4 h4;
        unsigned short* hh = (unsigned short*)&h4;
#pragma unroll
        for (int i = 0; i < 4; ++i) {
            float f = fv[i];
            s += f * f;
            hh[i] = f2bf_rtne(f);
        }
        hp[j] = h4;
    }
#pragma unroll
    for (int off = 32; off; off >>= 1) s += __shfl_down(s, off);
    if (lane == 0) *sq = s;
}

// ---------------------------------------------------------------------------
// pass 2: 256x256 8-phase MFMA GEMM, 16x16x32 (conflict-free swizzle),
// single bf16 segment: dots = xhi . phi  (p_lo dropped; error budget measured
// at 0.0625/0.33 with one rounded operand, sqrt(2)x with two).
// Round-0 schedule (single barrier per phase, compiler-counted lgkm waits);
// counted vmcnt(4) at ph4/ph8 only. LDS-staged coalesced f32x4 epilogue.
// out = dots^2 / (xsq + psq - 2*dots + eps)
// ---------------------------------------------------------------------------
__global__ __launch_bounds__(512, 2) void yat_mfma8(
    const unsigned short* __restrict__ Ahi, const unsigned short* __restrict__ Phi,
    const float* __restrict__ xsq, const float* __restrict__ psq,
    float* __restrict__ out, int M, int N, int K) {

    __shared__ __align__(128) char sm[131072];   // 2 slots x (A 32KB + B 32KB)
    const char* smc = (const char*)sm;

    const int t = threadIdx.x;
    const int lane = t & 63;
    const int wid = t >> 6;        // 0..7
    const int wm = wid >> 2;       // 0..1  (row half of block)
    const int wn = wid & 3;        // 0..3  (col quarter of block)

    // T1: bijective XCD swizzle (total % 8 == 0 guaranteed by launch guard)
    const int nbx = N >> 8;
    const int nby = M >> 8;
    const int total = nbx * nby;
    int bid = blockIdx.x;
    bid = (bid & 7) * (total >> 3) + (bid >> 3);
    const int by = bid / nbx;
    const int bx = bid - by * nbx;
    const int brow = by << 8;
    const int bcol = bx << 8;

    const int NKT = K >> 6;         // K-tiles (16)
    const int NIT = NKT >> 1;       // 8

    f32x4 acc[8][4];
#pragma unroll
    for (int i = 0; i < 8; ++i)
#pragma unroll
        for (int j = 0; j < 4; ++j) acc[i][j] = (f32x4){0.f, 0.f, 0.f, 0.f};

    const int arow = lane & 15;           // fragment row/col within 16
    const int kq16 = (lane >> 4) * 16;    // byte offset of k-slot within 32-k half

    // stage one half-tile (16KB, 2 x global_load_lds per wave) of tile kt.
    // ht: 0=A-rows[0,128) 1=A-rows[128,256) 2=B-rows[0,128) 3=B-rows[128,256)
    const int stg_colb = (((lane & 7) ^ (lane >> 3)) << 4);  // pre-swizzled src col
    const size_t rowBytes = (size_t)K * 2;
    auto stage_ht = [&](int kt, int ht) {
        const int slot = kt & 1;
        const unsigned short* base;
        int rowbase;
        if (ht < 2) { base = Ahi; rowbase = brow; }
        else        { base = Phi; rowbase = bcol; }
        const size_t k0b = (size_t)kt << 7;      // 64 elems * 2B
        const int half = ht & 1;
        char* lbase = (char*)sm + slot * 65536 + ((ht < 2) ? 0 : 32768) + half * 16384;
#pragma unroll
        for (int l = 0; l < 2; ++l) {
            int rl = (l * 8 + wid) * 8 + (lane >> 3);
            int grow = rowbase + half * 128 + rl;
            const char* src = (const char*)base + (size_t)grow * rowBytes + k0b + stg_colb;
            __builtin_amdgcn_global_load_lds(
                (const __attribute__((address_space(1))) void*)src,
                (__attribute__((address_space(3))) void*)(lbase + (l * 8 + wid) * 1024),
                16, 0, 0);
        }
    };

    bf16x8 af[4][2];              // current A-half frags (overwritten ph3/ph7)
    bf16x8 bf0[2][2], bf1[2][2];  // B-quarter frags, live across the tile

#define READ_A(slot, mh) do {                                                  \
    _Pragma("unroll")                                                          \
    for (int mi_ = 0; mi_ < 4; ++mi_) {                                        \
        int r_ = wm * 128 + (mh) * 64 + mi_ * 16 + arow;                       \
        const char* p_ = smc + (slot) * 65536 + r_ * 128;                      \
        int s_ = (r_ & 7) << 4;                                                \
        af[mi_][0] = *(const bf16x8*)(p_ + (kq16 ^ s_));                       \
        af[mi_][1] = *(const bf16x8*)(p_ + ((64 + kq16) ^ s_));                \
    }                                                                          \
} while (0)

#define READ_B(slot, nh, dst) do {                                             \
    _Pragma("unroll")                                                          \
    for (int ni_ = 0; ni_ < 2; ++ni_) {                                        \
        int r_ = wn * 64 + (nh) * 32 + ni_ * 16 + arow;                        \
        const char* p_ = smc + (slot) * 65536 + 32768 + r_ * 128;              \
        int s_ = (r_ & 7) << 4;                                                \
        dst[ni_][0] = *(const bf16x8*)(p_ + (kq16 ^ s_));                      \
        dst[ni_][1] = *(const bf16x8*)(p_ + ((64 + kq16) ^ s_));               \
    }                                                                          \
} while (0)

#define MFMA_Q(mh, nh, bset) do {                                              \
    __builtin_amdgcn_s_setprio(1);                                             \
    _Pragma("unroll")                                                          \
    for (int kk_ = 0; kk_ < 2; ++kk_)                                          \
        _Pragma("unroll")                                                      \
        for (int mi_ = 0; mi_ < 4; ++mi_)                                      \
            _Pragma("unroll")                                                  \
            for (int ni_ = 0; ni_ < 2; ++ni_)                                  \
                acc[(mh) * 4 + mi_][(nh) * 2 + ni_] =                          \
                    __builtin_amdgcn_mfma_f32_16x16x32_bf16(                   \
                        af[mi_][kk_], bset[ni_][kk_],                          \
                        acc[(mh) * 4 + mi_][(nh) * 2 + ni_], 0, 0, 0);         \
    __builtin_amdgcn_s_setprio(0);                                             \
} while (0)

#define PBAR() do {                                                            \
    __builtin_amdgcn_s_barrier();                                              \
    __builtin_amdgcn_sched_barrier(0);                                         \
    asm volatile("" ::: "memory");                                             \
} while (0)
#define VMCNT(n) asm volatile("s_waitcnt vmcnt(" #n ")" ::: "memory")

    // prologue: stage T0 fully + T1.B halves; T0 resident; barrier.
    stage_ht(0, 0); stage_ht(0, 1); stage_ht(0, 2); stage_ht(0, 3);
    stage_ht(1, 2); stage_ht(1, 3);
    VMCNT(4);
    PBAR();

    for (int it = 0; it < NIT; ++it) {
        const int T1 = 2 * it + 1, T2 = 2 * it + 2, T3 = 2 * it + 3;
        const bool more = (T2 < NKT);

        // ---- tile T0 (slot0) ----
        stage_ht(T1, 0);
        READ_A(0, 0); READ_B(0, 0, bf0);
        MFMA_Q(0, 0, bf0); PBAR();
        stage_ht(T1, 1);
        READ_B(0, 1, bf1);
        MFMA_Q(0, 1, bf1); PBAR();
        if (more) stage_ht(T2, 2);
        READ_A(0, 1);
        MFMA_Q(1, 0, bf0); PBAR();
        if (more) stage_ht(T2, 3);
        MFMA_Q(1, 1, bf1);
        if (more) { VMCNT(4); } else { VMCNT(0); }
        PBAR();

        // ---- tile T1 (slot1) ----
        if (more) stage_ht(T2, 0);
        READ_A(1, 0); READ_B(1, 0, bf0);
        MFMA_Q(0, 0, bf0); PBAR();
        if (more) stage_ht(T2, 1);
        READ_B(1, 1, bf1);
        MFMA_Q(0, 1, bf1); PBAR();
        if (more) stage_ht(T3, 2);
        READ_A(1, 1);
        MFMA_Q(1, 0, bf0); PBAR();
        if (more) stage_ht(T3, 3);
        MFMA_Q(1, 1, bf1);
        if (more) { VMCNT(4); }
        PBAR();
    }

#undef READ_A
#undef READ_B
#undef MFMA_Q
#undef PBAR
#undef VMCNT

    // epilogue: score = d^2 / (xsq + psq - 2d + eps), staged through LDS so
    // global stores are full 1KB-per-wave dwordx4 rows (no partial-line
    // write amplification). Two passes of 128 rows (wm half each).
    // Swizzle: logical (row,col) stored at physical col ^ swz(row),
    // swz(row) = ((row>>2)&1)<<4. Reader loads physical (lane*4)^swz —
    // which holds LOGICAL cols [lane*4,+3] — stores to bcol + lane*4.
    float* smf = (float*)sm;
#pragma unroll
    for (int pass = 0; pass < 2; ++pass) {
        __syncthreads();
        if (wm == pass) {
#pragma unroll
            for (int ni = 0; ni < 4; ++ni) {
                int lc = wn * 64 + ni * 16 + arow;
                float ps = psq[bcol + lc];
#pragma unroll
                for (int mi = 0; mi < 8; ++mi) {
                    f32x4 c = acc[mi][ni];
                    int lr0 = mi * 16 + (lane >> 4) * 4;   // local row, mult of 4
                    int grow0 = brow + pass * 128 + lr0;
                    float4 xs4 = *(const float4*)(xsq + grow0);
                    float xsv[4] = {xs4.x, xs4.y, xs4.z, xs4.w};
                    int lcs = lc ^ (((lr0 >> 2) & 1) << 4);  // phys col (same for j<4)
#pragma unroll
                    for (int j = 0; j < 4; ++j) {
                        float dv = c[j];
                        float denom = xsv[j] + ps - 2.0f * dv + EPS;
                        smf[(lr0 + j) * 256 + lcs] = dv * dv / denom;
                    }
                }
            }
        }
        __syncthreads();
#pragma unroll
        for (int rr = 0; rr < 16; ++rr) {
            int r = wid * 16 + rr;
            int swz = ((r >> 2) & 1) << 4;
            int c0 = lane * 4;                              // logical col
            f32x4 v = *(const f32x4*)(smf + r * 256 + (c0 ^ swz));
            *(f32x4*)(out + (size_t)(brow + pass * 128 + r) * N + bcol + c0) = v;
        }
    }
}

__global__ void yat_fallback(const float* __restrict__ x, const float* __restrict__ p,
                             float* __restrict__ out, int B, int P, int D) {
    __shared__ float xs[1024];
    int b = blockIdx.x;
    int pc = blockIdx.y * 256 + threadIdx.x;
    for (int i = threadIdx.x; i < D; i += 256) xs[i] = x[(size_t)b * D + i];
    __syncthreads();
    if (pc >= P) return;
    float dot = 0.f, psq = 0.f, xsq = 0.f;
    for (int k = 0; k < D; ++k) {
        float pv = p[(size_t)pc * D + k];
        float xv = xs[k];
        dot += xv * pv;
        psq += pv * pv;
        xsq += xv * xv;
    }
    float denom = xsq + psq - 2.f * dot + EPS;
    out[(size_t)b * P + pc] = dot * dot / denom;
}

extern "C" void kernel_launch(void* const* d_in, const int* in_sizes, int n_in,
                              void* d_out, int out_size, void* d_ws, size_t ws_size,
                              hipStream_t stream) {
    const float* x = (const float*)d_in[0];
    const float* p = (const float*)d_in[1];
    float* out = (float*)d_out;

    const int D = 1024;
    const int B = in_sizes[0] / D;
    const int P = in_sizes[1] / D;

    size_t need = ((size_t)B * D + (size_t)P * D) * 2 + ((size_t)B + P) * 4;
    int nblocks = (B / 256) * (P / 256);
    if (ws_size < need || (B % 256) || (P % 256) || (D % 64) || (nblocks % 8)) {
        yat_fallback<<<dim3(B, (P + 255) / 256), 256, 0, stream>>>(x, p, out, B, P, D);
        return;
    }

    unsigned short* xhi = (unsigned short*)d_ws;
    unsigned short* phi = xhi + (size_t)B * D;
    float* xsq = (float*)(phi + (size_t)P * D);
    float* psq = xsq + B;

    int nrows = B + P;
    split_all<<<(nrows + 3) / 4, 256, 0, stream>>>(x, p, xhi, phi, xsq, psq, B, P, D);

    yat_mfma8<<<dim3(nblocks), 512, 0, stream>>>(xhi, phi, xsq, psq, out, B, P, D);
}